// Round 19
// baseline (327.170 us; speedup 1.0000x reference)
//
#include <hip/hip_runtime.h>
#include <hip/hip_bf16.h>

typedef unsigned int uint;
typedef unsigned short ushort;
typedef __attribute__((ext_vector_type(8))) short bf16x8;
typedef __attribute__((ext_vector_type(4))) float f32x4;
typedef __attribute__((ext_vector_type(2))) float f32x2;
typedef __attribute__((ext_vector_type(4))) int i32x4;
typedef __attribute__((ext_vector_type(4))) float f32x4v;
typedef __attribute__((ext_vector_type(4))) uint u32x4;
typedef __attribute__((ext_vector_type(4))) ushort u16x4;

#define ELLCAP 64

// ---- bf16 helpers (f32 accumulate everywhere; bf16 only for stored tensors) ----
__device__ __forceinline__ float2 bf2f2(uint p) {
    float2 r;
    r.x = __uint_as_float(p << 16);
    r.y = __uint_as_float(p & 0xffff0000u);
    return r;
}
__device__ __forceinline__ ushort f2bf(float f) {
    uint u = __float_as_uint(f);
    return (ushort)((u + 0x7fffu + ((u >> 16) & 1u)) >> 16);
}
__device__ __forceinline__ uint packbf(float a, float b) {
    return (uint)f2bf(a) | ((uint)f2bf(b) << 16);
}

// ---------------- pack h0 + weight transpose/convert + workspace zeroing ----------------
__global__ void k_prepack(const float* __restrict__ xi, const float* __restrict__ si,
                          ushort* __restrict__ h,
                          const float* __restrict__ W1, const float* __restrict__ W2,
                          const float* __restrict__ Wg,
                          ushort* __restrict__ W1T, ushort* __restrict__ W2T,
                          ushort* __restrict__ WgT, u32x4* __restrict__ zbase,
                          int L, int n4, int nz16) {
    int i = blockIdx.x * 256 + threadIdx.x;
    if (i < n4) {
        int row = i >> 4, c4 = i & 15;
        f32x4v xv = __builtin_nontemporal_load(reinterpret_cast<const f32x4v*>(&xi[i * 4]));
        f32x4v sv = __builtin_nontemporal_load(reinterpret_cast<const f32x4v*>(&si[i * 4]));
        u16x4 xo, so;
        xo.x = f2bf(xv.x); xo.y = f2bf(xv.y); xo.z = f2bf(xv.z); xo.w = f2bf(xv.w);
        so.x = f2bf(sv.x); so.y = f2bf(sv.y); so.z = f2bf(sv.z); so.w = f2bf(sv.w);
        __builtin_nontemporal_store(xo, reinterpret_cast<u16x4*>(&h[(size_t)row * 128 + c4 * 4]));
        __builtin_nontemporal_store(so, reinterpret_cast<u16x4*>(&h[(size_t)row * 128 + 64 + c4 * 4]));
        return;
    }
    int t = i - n4;
    int n1 = L * 8192, n2 = L * 4096;
    if (t < n1) {
        int li = t >> 13, r = t & 8191, j = r >> 7, kk = r & 127;
        W1T[t] = f2bf(W1[(size_t)li * 8192 + kk * 64 + j]);
    } else if (t < n1 + n2) {
        int u = t - n1; int li = u >> 12, r = u & 4095, j = r >> 6, kk = r & 63;
        W2T[u] = f2bf(W2[(size_t)li * 4096 + kk * 64 + j]);
    } else if (t < n1 + 2 * n2) {
        int u = t - n1 - n2; int li = u >> 12, r = u & 4095, j = r >> 6, kk = r & 63;
        WgT[u] = f2bf(Wg[(size_t)li * 4096 + kk * 64 + j]);
    } else if (t < n1 + 2 * n2 + nz16) {
        u32x4 z = {0u, 0u, 0u, 0u};
        zbase[t - n1 - 2 * n2] = z;
    }
}

// ---------------- XCD-partitioned ELL fill ----------------
template<typename CT>
__global__ void k_fillp(const int* __restrict__ src, const int* __restrict__ dst,
                        int* __restrict__ cnt, CT* __restrict__ col,
                        int E, int pshift) {
    int part = blockIdx.x & 7;
    int chunk = blockIdx.x >> 3;
    int e = (chunk * 256 + threadIdx.x) * 4;
    if (e >= E) return;
    if (e + 3 < E) {
        i32x4 s = __builtin_nontemporal_load(reinterpret_cast<const i32x4*>(&src[e]));
        i32x4 d = __builtin_nontemporal_load(reinterpret_cast<const i32x4*>(&dst[e]));
        if ((d.x >> pshift) == part) { int p0 = atomicAdd(&cnt[d.x], 1); if (p0 < ELLCAP) col[(size_t)d.x * ELLCAP + p0] = (CT)s.x; }
        if ((d.y >> pshift) == part) { int p1 = atomicAdd(&cnt[d.y], 1); if (p1 < ELLCAP) col[(size_t)d.y * ELLCAP + p1] = (CT)s.y; }
        if ((d.z >> pshift) == part) { int p2 = atomicAdd(&cnt[d.z], 1); if (p2 < ELLCAP) col[(size_t)d.z * ELLCAP + p2] = (CT)s.z; }
        if ((d.w >> pshift) == part) { int p3 = atomicAdd(&cnt[d.w], 1); if (p3 < ELLCAP) col[(size_t)d.w * ELLCAP + p3] = (CT)s.w; }
    } else {
        for (int q = 0; q < 4; ++q)
            if (e + q < E) {
                int dd = dst[e + q];
                if ((dd >> pshift) == part) {
                    int pos = atomicAdd(&cnt[dd], 1);
                    if (pos < ELLCAP) col[(size_t)dd * ELLCAP + pos] = (CT)src[e + q];
                }
            }
    }
}

__global__ void k_dinv(const int* __restrict__ cnt, float* __restrict__ dinv, int N) {
    int v = blockIdx.x * 256 + threadIdx.x;
    if (v < N) dinv[v] = rsqrtf((float)cnt[v] + 1.0f);   // + self loop
}

// ---------------- quarter-wave gather (ELL) with 1-deep index prefetch ----------------
template<typename CT>
__global__ __launch_bounds__(256)
void k_agg(const uint* __restrict__ h32, const int* __restrict__ cnt,
           const float* __restrict__ dinv, const CT* __restrict__ col,
           uint* __restrict__ g32, uint* __restrict__ tb32, int N) {
    int w = threadIdx.x >> 6, l = threadIdx.x & 63;
    int v = blockIdx.x * 4 + w;
    if (v >= N) return;
    int q = l >> 4, j = l & 15;
    int deg = cnt[v];
    float dv = dinv[v];
    int len = deg > ELLCAP ? ELLCAP : deg;
    float sA[8] = {0.f, 0.f, 0.f, 0.f, 0.f, 0.f, 0.f, 0.f};
    float sW[8] = {0.f, 0.f, 0.f, 0.f, 0.f, 0.f, 0.f, 0.f};
    if (q == 0) {   // self term
        uint4 hv = *reinterpret_cast<const uint4*>(&h32[(size_t)v * 64 + 4 * j]);
        float2 f0 = bf2f2(hv.x), f1 = bf2f2(hv.y), f2 = bf2f2(hv.z), f3 = bf2f2(hv.w);
        sA[0] = f0.x; sA[1] = f0.y; sA[2] = f1.x; sA[3] = f1.y;
        sA[4] = f2.x; sA[5] = f2.y; sA[6] = f3.x; sA[7] = f3.y;
#pragma unroll
        for (int i = 0; i < 8; ++i) sW[i] = dv * sA[i];
    }
    const CT* cl = col + (size_t)v * ELLCAP;
    int len8 = len & ~7;
    int t = q;
    int u0 = 0, u1 = 0;
    if (t < len8) { u0 = cl[t]; u1 = cl[t + 4]; }
    for (; t < len8; ) {
        int nt = t + 8;
        int n0 = 0, n1 = 0;
        if (nt < len8) { n0 = cl[nt]; n1 = cl[nt + 4]; }   // prefetch next pair
        float d0 = dinv[u0], d1 = dinv[u1];
        uint4 a = *reinterpret_cast<const uint4*>(&h32[(size_t)u0 * 64 + 4 * j]);
        uint4 b = *reinterpret_cast<const uint4*>(&h32[(size_t)u1 * 64 + 4 * j]);
        float2 a0 = bf2f2(a.x), a1 = bf2f2(a.y), a2 = bf2f2(a.z), a3 = bf2f2(a.w);
        float2 b0 = bf2f2(b.x), b1 = bf2f2(b.y), b2 = bf2f2(b.z), b3 = bf2f2(b.w);
        float fa[8] = {a0.x, a0.y, a1.x, a1.y, a2.x, a2.y, a3.x, a3.y};
        float fb[8] = {b0.x, b0.y, b1.x, b1.y, b2.x, b2.y, b3.x, b3.y};
#pragma unroll
        for (int i = 0; i < 8; ++i) {
            sA[i] += fa[i] + fb[i];
            sW[i] = fmaf(d0, fa[i], fmaf(d1, fb[i], sW[i]));
        }
        t = nt; u0 = n0; u1 = n1;
    }
    for (; t < len; t += 4) {
        int u = cl[t];
        float du = dinv[u];
        uint4 a = *reinterpret_cast<const uint4*>(&h32[(size_t)u * 64 + 4 * j]);
        float2 a0 = bf2f2(a.x), a1 = bf2f2(a.y), a2 = bf2f2(a.z), a3 = bf2f2(a.w);
        float fa[8] = {a0.x, a0.y, a1.x, a1.y, a2.x, a2.y, a3.x, a3.y};
#pragma unroll
        for (int i = 0; i < 8; ++i) {
            sA[i] += fa[i];
            sW[i] = fmaf(du, fa[i], sW[i]);
        }
    }
#pragma unroll
    for (int i = 0; i < 8; ++i) {
        sA[i] += __shfl_xor(sA[i], 16); sA[i] += __shfl_xor(sA[i], 32);
        sW[i] += __shfl_xor(sW[i], 16); sW[i] += __shfl_xor(sW[i], 32);
    }
    if (q == 0) {
        u32x4 go;
        go.x = packbf(sA[0], sA[1]); go.y = packbf(sA[2], sA[3]);
        go.z = packbf(sA[4], sA[5]); go.w = packbf(sA[6], sA[7]);
        __builtin_nontemporal_store(go, reinterpret_cast<u32x4*>(&g32[(size_t)v * 64 + 4 * j]));
        if (j >= 8) {
            u32x4 to;
            to.x = packbf(dv * sW[0], dv * sW[1]); to.y = packbf(dv * sW[2], dv * sW[3]);
            to.z = packbf(dv * sW[4], dv * sW[5]); to.w = packbf(dv * sW[6], dv * sW[7]);
            __builtin_nontemporal_store(to, reinterpret_cast<u32x4*>(&tb32[(size_t)v * 32 + 4 * (j - 8)]));
        }
    }
}

// ---------------- MFMA layer: uniform 1-wave blocks; STATS via wave-reduce + global atomics ----------------
// LDS-transposed coalesced epilogue (round-16 win). No inter-wave coupling, no barriers.
template<bool STATS>
__global__ __launch_bounds__(64)
void k_layer_mfma(const ushort* __restrict__ g,   // [N][128] bf16
                  const ushort* __restrict__ tb,  // [N][64]  bf16
                  const ushort* __restrict__ W1T, // [64][128]
                  const ushort* __restrict__ W2T, // [64][64]
                  const ushort* __restrict__ WgT, // [64][64]
                  const float* __restrict__ bg,
                  ushort* __restrict__ hout, float* __restrict__ stats, int N) {
    __shared__ short sT[1024];    // 16x64 bf16 T-tile, XOR-swizzled (wave-private)
    __shared__ uint ot[16 * 66];  // out tile, row stride 66 uints (pad 2)
    int l = threadIdx.x & 63;
    int p = l >> 4, q16 = l & 15;
    int r0 = blockIdx.x * 16;
    int arow = r0 + q16; if (arow >= N) arow = N - 1;   // clamp: no OOB reads
    // ---- phase 0: issue independent loads (A, tb, W1) ----
    bf16x8 a[4], av[2], w1[16];
#pragma unroll
    for (int kt = 0; kt < 4; ++kt)
        a[kt] = *reinterpret_cast<const bf16x8*>(&g[(size_t)arow * 128 + kt * 32 + p * 8]);
#pragma unroll
    for (int kt = 0; kt < 2; ++kt)
        av[kt] = *reinterpret_cast<const bf16x8*>(&tb[(size_t)arow * 64 + kt * 32 + p * 8]);
#pragma unroll
    for (int kt = 0; kt < 4; ++kt)
#pragma unroll
        for (int jt = 0; jt < 4; ++jt)
            w1[kt * 4 + jt] = *reinterpret_cast<const bf16x8*>(&W1T[(size_t)(jt * 16 + q16) * 128 + kt * 32 + p * 8]);
    // ---- stage 1: T = g @ W1 ----
    f32x4 acc1[4] = {};
#pragma unroll
    for (int kt = 0; kt < 4; ++kt)
#pragma unroll
        for (int jt = 0; jt < 4; ++jt)
            acc1[jt] = __builtin_amdgcn_mfma_f32_16x16x32_bf16(a[kt], w1[kt * 4 + jt], acc1[jt], 0, 0, 0);
    // ---- issue W2/Wg loads (latency hides under stage-1 chain + LDS roundtrip) ----
    bf16x8 w2[8], w3[8];
#pragma unroll
    for (int kt = 0; kt < 2; ++kt)
#pragma unroll
        for (int jt = 0; jt < 4; ++jt) {
            int koff = kt * 32 + p * 8;
            w2[kt * 4 + jt] = *reinterpret_cast<const bf16x8*>(&W2T[(size_t)(jt * 16 + q16) * 64 + koff]);
            w3[kt * 4 + jt] = *reinterpret_cast<const bf16x8*>(&WgT[(size_t)(jt * 16 + q16) * 64 + koff]);
        }
    // ---- leaky + T-tile to LDS (wave-private, no barrier) ----
#pragma unroll
    for (int jt = 0; jt < 4; ++jt) {
#pragma unroll
        for (int q = 0; q < 4; ++q) {
            float v = acc1[jt][q];
            v = v > 0.f ? v : 0.01f * v;
            int m = 4 * p + q;
            int c = jt * 16 + q16;
            sT[m * 64 + (c ^ ((m & 7) << 3))] = (short)f2bf(v);
        }
    }
    // ---- stage 2: x' = T @ W2 ; stage 3: s'pre = tb @ Wg ----
    f32x4 acc2[4] = {}, acc3[4] = {};
#pragma unroll
    for (int kt = 0; kt < 2; ++kt) {
        int koff = kt * 32 + p * 8;
        bf16x8 at = *reinterpret_cast<const bf16x8*>(&sT[q16 * 64 + (koff ^ ((q16 & 7) << 3))]);
#pragma unroll
        for (int jt = 0; jt < 4; ++jt) {
            acc2[jt] = __builtin_amdgcn_mfma_f32_16x16x32_bf16(at, w2[kt * 4 + jt], acc2[jt], 0, 0, 0);
            acc3[jt] = __builtin_amdgcn_mfma_f32_16x16x32_bf16(av[kt], w3[kt * 4 + jt], acc3[jt], 0, 0, 0);
        }
    }
    // ---- epilogue: scatter to wave-private LDS tile, then coalesced stores ----
    {
        ushort* ots = (ushort*)ot;
#pragma unroll
        for (int jt = 0; jt < 4; ++jt) {
            int c = jt * 16 + q16;
            float bgv = bg[c];
#pragma unroll
            for (int q = 0; q < 4; ++q) {
                int m = 4 * p + q;
                ots[m * 132 + c] = f2bf(acc2[jt][q]);
                ots[m * 132 + 64 + c] = f2bf(tanhf(acc3[jt][q] + bgv));
            }
        }
        uint* hh = (uint*)hout;
        int row = l >> 2;
        int grow = r0 + row;
#pragma unroll
        for (int i = 0; i < 4; ++i) {
            int wd = (l & 3) * 4 + i * 16;
            u32x4 v = *reinterpret_cast<const u32x4*>(&ot[row * 66 + wd]);
            if (grow < N)
                *reinterpret_cast<u32x4*>(&hh[(size_t)grow * 64 + wd]) = v;
        }
    }
    if (STATS) {
        // wave-reduce column sums/sumsq over p, then direct global atomics (p==0 lanes)
#pragma unroll
        for (int jt = 0; jt < 4; ++jt) {
            float cs = 0.f, cq = 0.f;
#pragma unroll
            for (int q = 0; q < 4; ++q) {
                int row = r0 + 4 * p + q;
                if (row < N) {
                    float v = acc2[jt][q];
                    cs += v; cq += v * v;
                }
            }
            cs += __shfl_xor(cs, 16); cs += __shfl_xor(cs, 32);
            cq += __shfl_xor(cq, 16); cq += __shfl_xor(cq, 32);
            if (p == 0) {
                int c = jt * 16 + q16;
                atomicAdd(&stats[c], cs);
                atomicAdd(&stats[64 + c], cq);
            }
        }
    }
}

// ---------------- fused BN-apply + x_local write + per-graph pooled partials ----------------
__global__ __launch_bounds__(256)
void k_bnpool(const uint* __restrict__ h32, const float* __restrict__ stats,
              const float* __restrict__ gamma, const float* __restrict__ beta,
              const int* __restrict__ batch, float* __restrict__ xlocal,
              float* __restrict__ ph, int* __restrict__ pcnt, int N, int rpw) {
    int wg = blockIdx.x * 4 + (threadIdx.x >> 6);
    int l = threadIdx.x & 63;
    int r = wg * rpw;
    int rend = r + rpw; if (rend > N) rend = N;
    if (r >= rend) return;
    float invN = 1.0f / (float)N;
    bool isx = (l < 32);
    int f0 = 2 * l, f1 = 2 * l + 1;
    float mean0 = 0.f, mean1 = 0.f, inv0 = 1.f, inv1 = 1.f;
    float ga0 = 0.f, ga1 = 0.f, be0 = 0.f, be1 = 0.f;
    if (isx) {
        mean0 = stats[f0] * invN; mean1 = stats[f1] * invN;
        float v0 = stats[64 + f0] * invN - mean0 * mean0;
        float v1 = stats[64 + f1] * invN - mean1 * mean1;
        inv0 = rsqrtf(v0 + 1e-4f); inv1 = rsqrtf(v1 + 1e-4f);
        ga0 = gamma[f0]; ga1 = gamma[f1]; be0 = beta[f0]; be1 = beta[f1];
    }
    int cur = batch[r];
    float a0 = 0.f, a1 = 0.f; int cnt = 0;
    for (; r < rend; ++r) {
        int b = batch[r];
        if (b != cur) {
            atomicAdd(&ph[cur * 128 + f0], a0);
            atomicAdd(&ph[cur * 128 + f1], a1);
            if (l == 0) atomicAdd(&pcnt[cur], cnt);
            a0 = 0.f; a1 = 0.f; cnt = 0; cur = b;
        }
        float2 f = bf2f2(h32[(size_t)r * 64 + l]);
        if (isx) {
            float xn0 = fmaf((f.x - mean0) * inv0, ga0, be0);
            float xn1 = fmaf((f.y - mean1) * inv1, ga1, be1);
            f32x2 o; o.x = xn0; o.y = xn1;
            __builtin_nontemporal_store(o, reinterpret_cast<f32x2*>(&xlocal[(size_t)r * 64 + f0]));
            a0 += xn0; a1 += xn1;
        } else {
            a0 += f.x; a1 += f.y;
        }
        cnt++;
    }
    atomicAdd(&ph[cur * 128 + f0], a0);
    atomicAdd(&ph[cur * 128 + f1], a1);
    if (l == 0) atomicAdd(&pcnt[cur], cnt);
}

// ---------------- tiny final GEMM on pooled sums ----------------
__global__ __launch_bounds__(256)
void k_out(const float* __restrict__ ph, const int* __restrict__ pcnt,
           const float* __restrict__ Wh, const float* __restrict__ bh,
           float* __restrict__ pooled, int G) {
    int t = blockIdx.x * 256 + threadIdx.x;
    if (t >= G * 64) return;
    int g = t >> 6, j = t & 63;
    float acc = bh[j] * (float)pcnt[g];
    const float* row = ph + g * 128;
#pragma unroll 4
    for (int k = 0; k < 128; ++k) acc = fmaf(row[k], Wh[k * 64 + j], acc);
    pooled[t] = acc;
}

extern "C" void kernel_launch(void* const* d_in, const int* in_sizes, int n_in,
                              void* d_out, int out_size, void* d_ws, size_t ws_size,
                              hipStream_t stream) {
    const float* x_in  = (const float*)d_in[0];
    const float* s_in  = (const float*)d_in[1];
    const float* W1    = (const float*)d_in[2];
    const float* W2    = (const float*)d_in[3];
    const float* gamma = (const float*)d_in[4];
    const float* beta  = (const float*)d_in[5];
    const float* Wg    = (const float*)d_in[6];
    const float* bg    = (const float*)d_in[7];
    const float* Wh    = (const float*)d_in[8];
    const float* bh    = (const float*)d_in[9];
    const int*   ei    = (const int*)d_in[10];
    const int*   batch = (const int*)d_in[11];

    int N = in_sizes[0] / 64;
    int E = in_sizes[10] / 2;
    int L = in_sizes[2] / 8192;
    int G = out_size / 64 - N;

    const int* src = ei;
    const int* dst = ei + E;

    float* pooled = (float*)d_out;
    float* xlocal = pooled + (size_t)G * 64;      // final BN'd x (f32) output
    ushort* tb16  = (ushort*)xlocal;              // tb (bf16 N*64) borrows this slot during layers

    char* p = (char*)d_ws;
    auto alloc = [&](size_t bytes) { char* r = p; p += (bytes + 255) & ~(size_t)255; return r; };
    ushort* h16  = (ushort*)alloc((size_t)N * 128 * 2);
    ushort* g16  = (ushort*)alloc((size_t)N * 128 * 2);
    float* dinv  = (float*)alloc((size_t)N * 4);
    // single zeroed span: stats + ph + pcnt + cnt  (zeroed inside k_prepack)
    float* stats = (float*)alloc(128 * 4);
    float* ph    = (float*)alloc((size_t)G * 128 * 4);
    int* pcnt    = (int*)alloc((size_t)G * 4);
    int* cnt     = (int*)alloc((size_t)N * 4);
    char* zero_end = p;
    void* colv   = (void*)alloc((size_t)N * ELLCAP * 4);   // u16 path uses half
    ushort* W1T  = (ushort*)alloc((size_t)L * 8192 * 2);
    ushort* W2T  = (ushort*)alloc((size_t)L * 4096 * 2);
    ushort* WgT  = (ushort*)alloc((size_t)L * 4096 * 2);
    const uint* h32 = (const uint*)h16;
    uint* g32 = (uint*)g16;
    uint* tb32 = (uint*)tb16;

    int n4 = N * 16;
    int nprep = L * 16384;
    int nz16 = (int)(((size_t)(zero_end - (char*)stats)) >> 4);   // span is 256B-aligned
    int E4 = (E + 3) / 4;
    int nchunk = (E4 + 255) / 256;
    int packB = (n4 + nprep + nz16 + 255) / 256;
    int gBlk1 = (N + 15) / 16;   // 64-thread layer blocks

    // partition shift: smallest shift with (N-1)>>shift <= 7  (8 node ranges)
    int pshift = 0;
    while (((N - 1) >> pshift) > 7) pshift++;

    k_prepack<<<packB, 256, 0, stream>>>(x_in, s_in, h16, W1, W2, Wg, W1T, W2T, WgT,
                                         (u32x4*)stats, L, n4, nz16);

    if (N <= 65536) {
        ushort* col = (ushort*)colv;
        k_fillp<ushort><<<8 * nchunk, 256, 0, stream>>>(src, dst, cnt, col, E, pshift);
        k_dinv<<<(N + 255) / 256, 256, 0, stream>>>(cnt, dinv, N);
        for (int i = 0; i < L; ++i) {
            k_agg<ushort><<<(N + 3) / 4, 256, 0, stream>>>(h32, cnt, dinv, col, g32, tb32, N);
            if (i < L - 1)
                k_layer_mfma<false><<<gBlk1, 64, 0, stream>>>(g16, tb16,
                                                              W1T + (size_t)i * 8192, W2T + (size_t)i * 4096,
                                                              WgT + (size_t)i * 4096, bg + (size_t)i * 64,
                                                              h16, stats, N);
            else
                k_layer_mfma<true><<<gBlk1, 64, 0, stream>>>(g16, tb16,
                                                             W1T + (size_t)i * 8192, W2T + (size_t)i * 4096,
                                                             WgT + (size_t)i * 4096, bg + (size_t)i * 64,
                                                             h16, stats, N);
        }
    } else {
        int* col = (int*)colv;
        k_fillp<int><<<8 * nchunk, 256, 0, stream>>>(src, dst, cnt, col, E, pshift);
        k_dinv<<<(N + 255) / 256, 256, 0, stream>>>(cnt, dinv, N);
        for (int i = 0; i < L; ++i) {
            k_agg<int><<<(N + 3) / 4, 256, 0, stream>>>(h32, cnt, dinv, col, g32, tb32, N);
            if (i < L - 1)
                k_layer_mfma<false><<<gBlk1, 64, 0, stream>>>(g16, tb16,
                                                              W1T + (size_t)i * 8192, W2T + (size_t)i * 4096,
                                                              WgT + (size_t)i * 4096, bg + (size_t)i * 64,
                                                              h16, stats, N);
            else
                k_layer_mfma<true><<<gBlk1, 64, 0, stream>>>(g16, tb16,
                                                             W1T + (size_t)i * 8192, W2T + (size_t)i * 4096,
                                                             WgT + (size_t)i * 4096, bg + (size_t)i * 64,
                                                             h16, stats, N);
        }
    }

    int nwaves = 2048;
    int rpw = (N + nwaves - 1) / nwaves;
    k_bnpool<<<nwaves / 4, 256, 0, stream>>>(h32, stats,
                                             gamma + (size_t)(L - 1) * 64,
                                             beta + (size_t)(L - 1) * 64,
                                             batch, xlocal, ph, pcnt, N, rpw);
    k_out<<<(G * 64 + 255) / 256, 256, 0, stream>>>(ph, pcnt, Wh, bh, pooled, G);
}

// Round 20
// 272.688 us; speedup vs baseline: 1.1998x; 1.1998x over previous
//
#include <hip/hip_runtime.h>
#include <hip/hip_bf16.h>

typedef unsigned int uint;
typedef unsigned short ushort;
typedef __attribute__((ext_vector_type(8))) short bf16x8;
typedef __attribute__((ext_vector_type(4))) float f32x4;
typedef __attribute__((ext_vector_type(2))) float f32x2;
typedef __attribute__((ext_vector_type(4))) int i32x4;
typedef __attribute__((ext_vector_type(4))) float f32x4v;
typedef __attribute__((ext_vector_type(4))) uint u32x4;
typedef __attribute__((ext_vector_type(4))) ushort u16x4;

#define ELLCAP 64

// ---- bf16 helpers (f32 accumulate everywhere; bf16 only for stored tensors) ----
__device__ __forceinline__ float2 bf2f2(uint p) {
    float2 r;
    r.x = __uint_as_float(p << 16);
    r.y = __uint_as_float(p & 0xffff0000u);
    return r;
}
__device__ __forceinline__ ushort f2bf(float f) {
    uint u = __float_as_uint(f);
    return (ushort)((u + 0x7fffu + ((u >> 16) & 1u)) >> 16);
}
__device__ __forceinline__ uint packbf(float a, float b) {
    return (uint)f2bf(a) | ((uint)f2bf(b) << 16);
}

// ---------------- pack h0 + weight transpose/convert + workspace zeroing ----------------
// range [0,n4): pack x|s -> bf16 h rows; [n4,n4+nprep): weight transpose/convert;
// [n4+nprep, n4+nprep+nz16): zero the stats/ph/pcnt/cnt span (replaces hipMemsetAsync).
__global__ void k_prepack(const float* __restrict__ xi, const float* __restrict__ si,
                          ushort* __restrict__ h,
                          const float* __restrict__ W1, const float* __restrict__ W2,
                          const float* __restrict__ Wg,
                          ushort* __restrict__ W1T, ushort* __restrict__ W2T,
                          ushort* __restrict__ WgT, u32x4* __restrict__ zbase,
                          int L, int n4, int nz16) {
    int i = blockIdx.x * 256 + threadIdx.x;
    if (i < n4) {
        int row = i >> 4, c4 = i & 15;
        f32x4v xv = __builtin_nontemporal_load(reinterpret_cast<const f32x4v*>(&xi[i * 4]));
        f32x4v sv = __builtin_nontemporal_load(reinterpret_cast<const f32x4v*>(&si[i * 4]));
        u16x4 xo, so;
        xo.x = f2bf(xv.x); xo.y = f2bf(xv.y); xo.z = f2bf(xv.z); xo.w = f2bf(xv.w);
        so.x = f2bf(sv.x); so.y = f2bf(sv.y); so.z = f2bf(sv.z); so.w = f2bf(sv.w);
        __builtin_nontemporal_store(xo, reinterpret_cast<u16x4*>(&h[(size_t)row * 128 + c4 * 4]));
        __builtin_nontemporal_store(so, reinterpret_cast<u16x4*>(&h[(size_t)row * 128 + 64 + c4 * 4]));
        return;
    }
    int t = i - n4;
    int n1 = L * 8192, n2 = L * 4096;
    if (t < n1) {
        int li = t >> 13, r = t & 8191, j = r >> 7, kk = r & 127;
        W1T[t] = f2bf(W1[(size_t)li * 8192 + kk * 64 + j]);
    } else if (t < n1 + n2) {
        int u = t - n1; int li = u >> 12, r = u & 4095, j = r >> 6, kk = r & 63;
        W2T[u] = f2bf(W2[(size_t)li * 4096 + kk * 64 + j]);
    } else if (t < n1 + 2 * n2) {
        int u = t - n1 - n2; int li = u >> 12, r = u & 4095, j = r >> 6, kk = r & 63;
        WgT[u] = f2bf(Wg[(size_t)li * 4096 + kk * 64 + j]);
    } else if (t < n1 + 2 * n2 + nz16) {
        u32x4 z = {0u, 0u, 0u, 0u};
        zbase[t - n1 - 2 * n2] = z;
    }
}

// ---------------- XCD-partitioned ELL fill ----------------
template<typename CT>
__global__ void k_fillp(const int* __restrict__ src, const int* __restrict__ dst,
                        int* __restrict__ cnt, CT* __restrict__ col,
                        int E, int pshift) {
    int part = blockIdx.x & 7;
    int chunk = blockIdx.x >> 3;
    int e = (chunk * 256 + threadIdx.x) * 4;
    if (e >= E) return;
    if (e + 3 < E) {
        i32x4 s = __builtin_nontemporal_load(reinterpret_cast<const i32x4*>(&src[e]));
        i32x4 d = __builtin_nontemporal_load(reinterpret_cast<const i32x4*>(&dst[e]));
        if ((d.x >> pshift) == part) { int p0 = atomicAdd(&cnt[d.x], 1); if (p0 < ELLCAP) col[(size_t)d.x * ELLCAP + p0] = (CT)s.x; }
        if ((d.y >> pshift) == part) { int p1 = atomicAdd(&cnt[d.y], 1); if (p1 < ELLCAP) col[(size_t)d.y * ELLCAP + p1] = (CT)s.y; }
        if ((d.z >> pshift) == part) { int p2 = atomicAdd(&cnt[d.z], 1); if (p2 < ELLCAP) col[(size_t)d.z * ELLCAP + p2] = (CT)s.z; }
        if ((d.w >> pshift) == part) { int p3 = atomicAdd(&cnt[d.w], 1); if (p3 < ELLCAP) col[(size_t)d.w * ELLCAP + p3] = (CT)s.w; }
    } else {
        for (int q = 0; q < 4; ++q)
            if (e + q < E) {
                int dd = dst[e + q];
                if ((dd >> pshift) == part) {
                    int pos = atomicAdd(&cnt[dd], 1);
                    if (pos < ELLCAP) col[(size_t)dd * ELLCAP + pos] = (CT)src[e + q];
                }
            }
    }
}

__global__ void k_dinv(const int* __restrict__ cnt, float* __restrict__ dinv, int N) {
    int v = blockIdx.x * 256 + threadIdx.x;
    if (v < N) dinv[v] = rsqrtf((float)cnt[v] + 1.0f);   // + self loop
}

// ---------------- quarter-wave gather (ELL) with 1-deep index prefetch ----------------
template<typename CT>
__global__ __launch_bounds__(256)
void k_agg(const uint* __restrict__ h32, const int* __restrict__ cnt,
           const float* __restrict__ dinv, const CT* __restrict__ col,
           uint* __restrict__ g32, uint* __restrict__ tb32, int N) {
    int w = threadIdx.x >> 6, l = threadIdx.x & 63;
    int v = blockIdx.x * 4 + w;
    if (v >= N) return;
    int q = l >> 4, j = l & 15;
    int deg = cnt[v];
    float dv = dinv[v];
    int len = deg > ELLCAP ? ELLCAP : deg;
    float sA[8] = {0.f, 0.f, 0.f, 0.f, 0.f, 0.f, 0.f, 0.f};
    float sW[8] = {0.f, 0.f, 0.f, 0.f, 0.f, 0.f, 0.f, 0.f};
    if (q == 0) {   // self term
        uint4 hv = *reinterpret_cast<const uint4*>(&h32[(size_t)v * 64 + 4 * j]);
        float2 f0 = bf2f2(hv.x), f1 = bf2f2(hv.y), f2 = bf2f2(hv.z), f3 = bf2f2(hv.w);
        sA[0] = f0.x; sA[1] = f0.y; sA[2] = f1.x; sA[3] = f1.y;
        sA[4] = f2.x; sA[5] = f2.y; sA[6] = f3.x; sA[7] = f3.y;
#pragma unroll
        for (int i = 0; i < 8; ++i) sW[i] = dv * sA[i];
    }
    const CT* cl = col + (size_t)v * ELLCAP;
    int len8 = len & ~7;
    int t = q;
    int u0 = 0, u1 = 0;
    if (t < len8) { u0 = cl[t]; u1 = cl[t + 4]; }
    for (; t < len8; ) {
        int nt = t + 8;
        int n0 = 0, n1 = 0;
        if (nt < len8) { n0 = cl[nt]; n1 = cl[nt + 4]; }   // prefetch next pair
        float d0 = dinv[u0], d1 = dinv[u1];
        uint4 a = *reinterpret_cast<const uint4*>(&h32[(size_t)u0 * 64 + 4 * j]);
        uint4 b = *reinterpret_cast<const uint4*>(&h32[(size_t)u1 * 64 + 4 * j]);
        float2 a0 = bf2f2(a.x), a1 = bf2f2(a.y), a2 = bf2f2(a.z), a3 = bf2f2(a.w);
        float2 b0 = bf2f2(b.x), b1 = bf2f2(b.y), b2 = bf2f2(b.z), b3 = bf2f2(b.w);
        float fa[8] = {a0.x, a0.y, a1.x, a1.y, a2.x, a2.y, a3.x, a3.y};
        float fb[8] = {b0.x, b0.y, b1.x, b1.y, b2.x, b2.y, b3.x, b3.y};
#pragma unroll
        for (int i = 0; i < 8; ++i) {
            sA[i] += fa[i] + fb[i];
            sW[i] = fmaf(d0, fa[i], fmaf(d1, fb[i], sW[i]));
        }
        t = nt; u0 = n0; u1 = n1;
    }
    for (; t < len; t += 4) {
        int u = cl[t];
        float du = dinv[u];
        uint4 a = *reinterpret_cast<const uint4*>(&h32[(size_t)u * 64 + 4 * j]);
        float2 a0 = bf2f2(a.x), a1 = bf2f2(a.y), a2 = bf2f2(a.z), a3 = bf2f2(a.w);
        float fa[8] = {a0.x, a0.y, a1.x, a1.y, a2.x, a2.y, a3.x, a3.y};
#pragma unroll
        for (int i = 0; i < 8; ++i) {
            sA[i] += fa[i];
            sW[i] = fmaf(du, fa[i], sW[i]);
        }
    }
#pragma unroll
    for (int i = 0; i < 8; ++i) {
        sA[i] += __shfl_xor(sA[i], 16); sA[i] += __shfl_xor(sA[i], 32);
        sW[i] += __shfl_xor(sW[i], 16); sW[i] += __shfl_xor(sW[i], 32);
    }
    if (q == 0) {
        u32x4 go;
        go.x = packbf(sA[0], sA[1]); go.y = packbf(sA[2], sA[3]);
        go.z = packbf(sA[4], sA[5]); go.w = packbf(sA[6], sA[7]);
        __builtin_nontemporal_store(go, reinterpret_cast<u32x4*>(&g32[(size_t)v * 64 + 4 * j]));
        if (j >= 8) {
            u32x4 to;
            to.x = packbf(dv * sW[0], dv * sW[1]); to.y = packbf(dv * sW[2], dv * sW[3]);
            to.z = packbf(dv * sW[4], dv * sW[5]); to.w = packbf(dv * sW[6], dv * sW[7]);
            __builtin_nontemporal_store(to, reinterpret_cast<u32x4*>(&tb32[(size_t)v * 32 + 4 * (j - 8)]));
        }
    }
}

// ---------------- MFMA layer: NW waves/block (NW=1 for max grid-level balance) ----------------
// LDS-transposed coalesced epilogue (round-16 win). No inter-wave coupling when NW=1.
template<int NW, bool STATS>
__global__ __launch_bounds__(NW * 64)
void k_layer_mfma(const ushort* __restrict__ g,   // [N][128] bf16
                  const ushort* __restrict__ tb,  // [N][64]  bf16
                  const ushort* __restrict__ W1T, // [64][128]
                  const ushort* __restrict__ W2T, // [64][64]
                  const ushort* __restrict__ WgT, // [64][64]
                  const float* __restrict__ bg,
                  ushort* __restrict__ hout, float* __restrict__ stats, int N) {
    __shared__ short sT[NW][1024];    // per-wave 16x64 bf16 T-tile, XOR-swizzled
    __shared__ uint ot[NW][16 * 66];  // per-wave out tile, row stride 66 uints (pad 2)
    __shared__ float bsum[64], bsq[64];
    int w = threadIdx.x >> 6, l = threadIdx.x & 63;
    int p = l >> 4, q16 = l & 15;
    int r0 = blockIdx.x * (16 * NW) + w * 16;
    int arow = r0 + q16; if (arow >= N) arow = N - 1;   // clamp: no OOB reads
    if (STATS) {
        if (threadIdx.x < 64) { bsum[threadIdx.x] = 0.f; bsq[threadIdx.x] = 0.f; }
        __syncthreads();
    }
    // ---- phase 0: issue independent loads (A, tb, W1) ----
    bf16x8 a[4], av[2], w1[16];
#pragma unroll
    for (int kt = 0; kt < 4; ++kt)
        a[kt] = *reinterpret_cast<const bf16x8*>(&g[(size_t)arow * 128 + kt * 32 + p * 8]);
#pragma unroll
    for (int kt = 0; kt < 2; ++kt)
        av[kt] = *reinterpret_cast<const bf16x8*>(&tb[(size_t)arow * 64 + kt * 32 + p * 8]);
#pragma unroll
    for (int kt = 0; kt < 4; ++kt)
#pragma unroll
        for (int jt = 0; jt < 4; ++jt)
            w1[kt * 4 + jt] = *reinterpret_cast<const bf16x8*>(&W1T[(size_t)(jt * 16 + q16) * 128 + kt * 32 + p * 8]);
    // ---- stage 1: T = g @ W1 ----
    f32x4 acc1[4] = {};
#pragma unroll
    for (int kt = 0; kt < 4; ++kt)
#pragma unroll
        for (int jt = 0; jt < 4; ++jt)
            acc1[jt] = __builtin_amdgcn_mfma_f32_16x16x32_bf16(a[kt], w1[kt * 4 + jt], acc1[jt], 0, 0, 0);
    // ---- issue W2/Wg loads (latency hides under stage-1 chain + LDS roundtrip) ----
    bf16x8 w2[8], w3[8];
#pragma unroll
    for (int kt = 0; kt < 2; ++kt)
#pragma unroll
        for (int jt = 0; jt < 4; ++jt) {
            int koff = kt * 32 + p * 8;
            w2[kt * 4 + jt] = *reinterpret_cast<const bf16x8*>(&W2T[(size_t)(jt * 16 + q16) * 64 + koff]);
            w3[kt * 4 + jt] = *reinterpret_cast<const bf16x8*>(&WgT[(size_t)(jt * 16 + q16) * 64 + koff]);
        }
    // ---- leaky + T-tile to (wave-private) LDS ----
#pragma unroll
    for (int jt = 0; jt < 4; ++jt) {
#pragma unroll
        for (int q = 0; q < 4; ++q) {
            float v = acc1[jt][q];
            v = v > 0.f ? v : 0.01f * v;
            int m = 4 * p + q;
            int c = jt * 16 + q16;
            sT[w][m * 64 + (c ^ ((m & 7) << 3))] = (short)f2bf(v);
        }
    }
    // ---- stage 2: x' = T @ W2 ; stage 3: s'pre = tb @ Wg ----
    f32x4 acc2[4] = {}, acc3[4] = {};
#pragma unroll
    for (int kt = 0; kt < 2; ++kt) {
        int koff = kt * 32 + p * 8;
        bf16x8 at = *reinterpret_cast<const bf16x8*>(&sT[w][q16 * 64 + (koff ^ ((q16 & 7) << 3))]);
#pragma unroll
        for (int jt = 0; jt < 4; ++jt) {
            acc2[jt] = __builtin_amdgcn_mfma_f32_16x16x32_bf16(at, w2[kt * 4 + jt], acc2[jt], 0, 0, 0);
            acc3[jt] = __builtin_amdgcn_mfma_f32_16x16x32_bf16(av[kt], w3[kt * 4 + jt], acc3[jt], 0, 0, 0);
        }
    }
    // ---- epilogue: scatter to wave-private LDS tile, then coalesced stores ----
    {
        ushort* ots = (ushort*)ot[w];
#pragma unroll
        for (int jt = 0; jt < 4; ++jt) {
            int c = jt * 16 + q16;
            float bgv = bg[c];
#pragma unroll
            for (int q = 0; q < 4; ++q) {
                int m = 4 * p + q;
                ots[m * 132 + c] = f2bf(acc2[jt][q]);
                ots[m * 132 + 64 + c] = f2bf(tanhf(acc3[jt][q] + bgv));
            }
        }
        uint* hh = (uint*)hout;
        int row = l >> 2;
        int grow = r0 + row;
#pragma unroll
        for (int i = 0; i < 4; ++i) {
            int wd = (l & 3) * 4 + i * 16;
            u32x4 v = *reinterpret_cast<const u32x4*>(&ot[w][row * 66 + wd]);
            if (grow < N)
                *reinterpret_cast<u32x4*>(&hh[(size_t)grow * 64 + wd]) = v;
        }
    }
    if (STATS) {
#pragma unroll
        for (int jt = 0; jt < 4; ++jt) {
            float cs = 0.f, cq = 0.f;
#pragma unroll
            for (int q = 0; q < 4; ++q) {
                int row = r0 + 4 * p + q;
                if (row < N) {
                    float v = acc2[jt][q];
                    cs += v; cq += v * v;
                }
            }
            cs += __shfl_xor(cs, 16); cs += __shfl_xor(cs, 32);
            cq += __shfl_xor(cq, 16); cq += __shfl_xor(cq, 32);
            if (p == 0) {
                int c = jt * 16 + q16;
                atomicAdd(&bsum[c], cs);
                atomicAdd(&bsq[c], cq);
            }
        }
        __syncthreads();
        if (threadIdx.x < 64) {
            atomicAdd(&stats[threadIdx.x], bsum[threadIdx.x]);
            atomicAdd(&stats[64 + threadIdx.x], bsq[threadIdx.x]);
        }
    }
}

// ---------------- fused BN-apply + x_local write + per-graph pooled partials ----------------
__global__ __launch_bounds__(256)
void k_bnpool(const uint* __restrict__ h32, const float* __restrict__ stats,
              const float* __restrict__ gamma, const float* __restrict__ beta,
              const int* __restrict__ batch, float* __restrict__ xlocal,
              float* __restrict__ ph, int* __restrict__ pcnt, int N, int rpw) {
    int wg = blockIdx.x * 4 + (threadIdx.x >> 6);
    int l = threadIdx.x & 63;
    int r = wg * rpw;
    int rend = r + rpw; if (rend > N) rend = N;
    if (r >= rend) return;
    float invN = 1.0f / (float)N;
    bool isx = (l < 32);
    int f0 = 2 * l, f1 = 2 * l + 1;
    float mean0 = 0.f, mean1 = 0.f, inv0 = 1.f, inv1 = 1.f;
    float ga0 = 0.f, ga1 = 0.f, be0 = 0.f, be1 = 0.f;
    if (isx) {
        mean0 = stats[f0] * invN; mean1 = stats[f1] * invN;
        float v0 = stats[64 + f0] * invN - mean0 * mean0;
        float v1 = stats[64 + f1] * invN - mean1 * mean1;
        inv0 = rsqrtf(v0 + 1e-4f); inv1 = rsqrtf(v1 + 1e-4f);
        ga0 = gamma[f0]; ga1 = gamma[f1]; be0 = beta[f0]; be1 = beta[f1];
    }
    int cur = batch[r];
    float a0 = 0.f, a1 = 0.f; int cnt = 0;
    for (; r < rend; ++r) {
        int b = batch[r];
        if (b != cur) {
            atomicAdd(&ph[cur * 128 + f0], a0);
            atomicAdd(&ph[cur * 128 + f1], a1);
            if (l == 0) atomicAdd(&pcnt[cur], cnt);
            a0 = 0.f; a1 = 0.f; cnt = 0; cur = b;
        }
        float2 f = bf2f2(h32[(size_t)r * 64 + l]);
        if (isx) {
            float xn0 = fmaf((f.x - mean0) * inv0, ga0, be0);
            float xn1 = fmaf((f.y - mean1) * inv1, ga1, be1);
            f32x2 o; o.x = xn0; o.y = xn1;
            __builtin_nontemporal_store(o, reinterpret_cast<f32x2*>(&xlocal[(size_t)r * 64 + f0]));
            a0 += xn0; a1 += xn1;
        } else {
            a0 += f.x; a1 += f.y;
        }
        cnt++;
    }
    atomicAdd(&ph[cur * 128 + f0], a0);
    atomicAdd(&ph[cur * 128 + f1], a1);
    if (l == 0) atomicAdd(&pcnt[cur], cnt);
}

// ---------------- tiny final GEMM on pooled sums ----------------
__global__ __launch_bounds__(256)
void k_out(const float* __restrict__ ph, const int* __restrict__ pcnt,
           const float* __restrict__ Wh, const float* __restrict__ bh,
           float* __restrict__ pooled, int G) {
    int t = blockIdx.x * 256 + threadIdx.x;
    if (t >= G * 64) return;
    int g = t >> 6, j = t & 63;
    float acc = bh[j] * (float)pcnt[g];
    const float* row = ph + g * 128;
#pragma unroll 4
    for (int k = 0; k < 128; ++k) acc = fmaf(row[k], Wh[k * 64 + j], acc);
    pooled[t] = acc;
}

extern "C" void kernel_launch(void* const* d_in, const int* in_sizes, int n_in,
                              void* d_out, int out_size, void* d_ws, size_t ws_size,
                              hipStream_t stream) {
    const float* x_in  = (const float*)d_in[0];
    const float* s_in  = (const float*)d_in[1];
    const float* W1    = (const float*)d_in[2];
    const float* W2    = (const float*)d_in[3];
    const float* gamma = (const float*)d_in[4];
    const float* beta  = (const float*)d_in[5];
    const float* Wg    = (const float*)d_in[6];
    const float* bg    = (const float*)d_in[7];
    const float* Wh    = (const float*)d_in[8];
    const float* bh    = (const float*)d_in[9];
    const int*   ei    = (const int*)d_in[10];
    const int*   batch = (const int*)d_in[11];

    int N = in_sizes[0] / 64;
    int E = in_sizes[10] / 2;
    int L = in_sizes[2] / 8192;
    int G = out_size / 64 - N;

    const int* src = ei;
    const int* dst = ei + E;

    float* pooled = (float*)d_out;
    float* xlocal = pooled + (size_t)G * 64;      // final BN'd x (f32) output
    ushort* tb16  = (ushort*)xlocal;              // tb (bf16 N*64) borrows this slot during layers

    char* p = (char*)d_ws;
    auto alloc = [&](size_t bytes) { char* r = p; p += (bytes + 255) & ~(size_t)255; return r; };
    ushort* h16  = (ushort*)alloc((size_t)N * 128 * 2);
    ushort* g16  = (ushort*)alloc((size_t)N * 128 * 2);
    float* dinv  = (float*)alloc((size_t)N * 4);
    // single zeroed span: stats + ph + pcnt + cnt  (zeroed inside k_prepack)
    float* stats = (float*)alloc(128 * 4);
    float* ph    = (float*)alloc((size_t)G * 128 * 4);
    int* pcnt    = (int*)alloc((size_t)G * 4);
    int* cnt     = (int*)alloc((size_t)N * 4);
    char* zero_end = p;
    void* colv   = (void*)alloc((size_t)N * ELLCAP * 4);   // u16 path uses half
    ushort* W1T  = (ushort*)alloc((size_t)L * 8192 * 2);
    ushort* W2T  = (ushort*)alloc((size_t)L * 4096 * 2);
    ushort* WgT  = (ushort*)alloc((size_t)L * 4096 * 2);
    const uint* h32 = (const uint*)h16;
    uint* g32 = (uint*)g16;
    uint* tb32 = (uint*)tb16;

    int n4 = N * 16;
    int nprep = L * 16384;
    int nz16 = (int)(((size_t)(zero_end - (char*)stats)) >> 4);   // span is 256B-aligned
    int E4 = (E + 3) / 4;
    int nchunk = (E4 + 255) / 256;
    int packB = (n4 + nprep + nz16 + 255) / 256;
    int gBlk1 = (N + 15) / 16;   // 64-thread layer blocks
    int gBlk4 = (N + 63) / 64;   // 256-thread STATS layer blocks

    // partition shift: smallest shift with (N-1)>>shift <= 7  (8 node ranges)
    int pshift = 0;
    while (((N - 1) >> pshift) > 7) pshift++;

    k_prepack<<<packB, 256, 0, stream>>>(x_in, s_in, h16, W1, W2, Wg, W1T, W2T, WgT,
                                         (u32x4*)stats, L, n4, nz16);

    if (N <= 65536) {
        ushort* col = (ushort*)colv;
        k_fillp<ushort><<<8 * nchunk, 256, 0, stream>>>(src, dst, cnt, col, E, pshift);
        k_dinv<<<(N + 255) / 256, 256, 0, stream>>>(cnt, dinv, N);
        for (int i = 0; i < L; ++i) {
            k_agg<ushort><<<(N + 3) / 4, 256, 0, stream>>>(h32, cnt, dinv, col, g32, tb32, N);
            if (i < L - 1)
                k_layer_mfma<1, false><<<gBlk1, 64, 0, stream>>>(g16, tb16,
                                                                 W1T + (size_t)i * 8192, W2T + (size_t)i * 4096,
                                                                 WgT + (size_t)i * 4096, bg + (size_t)i * 64,
                                                                 h16, stats, N);
            else
                k_layer_mfma<4, true><<<gBlk4, 256, 0, stream>>>(g16, tb16,
                                                                 W1T + (size_t)i * 8192, W2T + (size_t)i * 4096,
                                                                 WgT + (size_t)i * 4096, bg + (size_t)i * 64,
                                                                 h16, stats, N);
        }
    } else {
        int* col = (int*)colv;
        k_fillp<int><<<8 * nchunk, 256, 0, stream>>>(src, dst, cnt, col, E, pshift);
        k_dinv<<<(N + 255) / 256, 256, 0, stream>>>(cnt, dinv, N);
        for (int i = 0; i < L; ++i) {
            k_agg<int><<<(N + 3) / 4, 256, 0, stream>>>(h32, cnt, dinv, col, g32, tb32, N);
            if (i < L - 1)
                k_layer_mfma<1, false><<<gBlk1, 64, 0, stream>>>(g16, tb16,
                                                                 W1T + (size_t)i * 8192, W2T + (size_t)i * 4096,
                                                                 WgT + (size_t)i * 4096, bg + (size_t)i * 64,
                                                                 h16, stats, N);
            else
                k_layer_mfma<4, true><<<gBlk4, 256, 0, stream>>>(g16, tb16,
                                                                 W1T + (size_t)i * 8192, W2T + (size_t)i * 4096,
                                                                 WgT + (size_t)i * 4096, bg + (size_t)i * 64,
                                                                 h16, stats, N);
        }
    }

    int nwaves = 2048;
    int rpw = (N + nwaves - 1) / nwaves;
    k_bnpool<<<nwaves / 4, 256, 0, stream>>>(h32, stats,
                                             gamma + (size_t)(L - 1) * 64,
                                             beta + (size_t)(L - 1) * 64,
                                             batch, xlocal, ph, pcnt, N, rpw);
    k_out<<<(G * 64 + 255) / 256, 256, 0, stream>>>(ph, pcnt, Wh, bh, pooled, G);
}